// Round 7
// baseline (734.133 us; speedup 1.0000x reference)
//
#include <hip/hip_runtime.h>
#include <hip/hip_bf16.h>

typedef __bf16 bf16_t;
typedef __attribute__((ext_vector_type(8))) __bf16 bf16x8;
typedef __attribute__((ext_vector_type(4))) float f32x4;

constexpr int IN_F  = 4096;
constexpr int OUT_F = 16384;
constexpr int N_TOK = 8192;
constexpr int KSEL  = 8192;
constexpr long A_ELEMS = (long)N_TOK * IN_F;

constexpr int BM = 256, BN = 256, BK = 64;
constexpr int NT = IN_F / BK;        // 64 K-tiles
constexpr int HALF_E = 128 * BK;     // 8192 elems per half-tile

#define GLOBAL_CAST(p) (const __attribute__((address_space(1))) void*)(p)
#define LDS_CAST(p)    (__attribute__((address_space(3))) void*)(p)

// ---------------------------------------------------------------------------
// Kernel 1: idx[] = positions of mask==1 (ascending) + gather bias (fp32).
// ---------------------------------------------------------------------------
__global__ __launch_bounds__(1024) void build_idx_kernel(
    const int* __restrict__ mask, const float* __restrict__ bias,
    int* __restrict__ idx, float* __restrict__ bsel)
{
    const int t    = threadIdx.x;
    const int lane = t & 63;
    const int wave = t >> 6;
    const int base_i = t * 16;

    int m[16];
    const int4* mp = (const int4*)(mask + base_i);
#pragma unroll
    for (int v = 0; v < 4; ++v) {
        int4 q = mp[v];
        m[v*4+0] = q.x; m[v*4+1] = q.y; m[v*4+2] = q.z; m[v*4+3] = q.w;
    }
    int cnt = 0;
#pragma unroll
    for (int j = 0; j < 16; ++j) cnt += (m[j] != 0) ? 1 : 0;

    int incl = cnt;
#pragma unroll
    for (int d = 1; d < 64; d <<= 1) {
        int o = __shfl_up(incl, (unsigned)d);
        if (lane >= d) incl += o;
    }

    __shared__ int wsum[16];
    __shared__ int wbase[16];
    if (lane == 63) wsum[wave] = incl;
    __syncthreads();
    if (t == 0) {
        int s = 0;
        for (int w = 0; w < 16; ++w) { wbase[w] = s; s += wsum[w]; }
    }
    __syncthreads();

    int p = wbase[wave] + (incl - cnt);
#pragma unroll
    for (int j = 0; j < 16; ++j) {
        if (m[j]) {
            int i = base_i + j;
            idx[p]  = i;
            bsel[p] = bias[i];
            ++p;
        }
    }
}

// ---------------------------------------------------------------------------
// Kernel 2: fp32 -> bf16 convert; A straight, W gathered by idx.
// ---------------------------------------------------------------------------
__global__ __launch_bounds__(256) void convert_kernel(
    const float* __restrict__ A, const float* __restrict__ W,
    const int* __restrict__ idx,
    bf16_t* __restrict__ Ab, bf16_t* __restrict__ Wb)
{
    const long nvecA = A_ELEMS / 8;
    const long total = nvecA * 2;
    const long stride = (long)gridDim.x * blockDim.x;
    for (long v = (long)blockIdx.x * blockDim.x + threadIdx.x; v < total; v += stride) {
        const float4* src;
        bf16_t* dst;
        if (v < nvecA) {
            src = (const float4*)(A + v * 8);
            dst = Ab + v * 8;
        } else {
            long u = v - nvecA;
            int j = (int)(u >> 9);
            int k = (int)(u & 511) * 8;
            src = (const float4*)(W + (long)idx[j] * IN_F + k);
            dst = Wb + u * 8;
        }
        float4 x = src[0], y = src[1];
        bf16x8 o;
        o[0]=(bf16_t)x.x; o[1]=(bf16_t)x.y; o[2]=(bf16_t)x.z; o[3]=(bf16_t)x.w;
        o[4]=(bf16_t)y.x; o[5]=(bf16_t)y.y; o[6]=(bf16_t)y.z; o[7]=(bf16_t)y.w;
        *(bf16x8*)dst = o;
    }
}

// ---------------------------------------------------------------------------
// Kernel 3: m201-style 8-phase 256x256 GEMM, BK=64, 8 waves (2Mx4N),
// 2-deep dbuf, half-tile staging, counted vmcnt(4) at phases 4/8 only
// (vmcnt(0) at ph4 in the tail iteration - drains the last tile fully),
// XOR slot swizzle via pre-swizzled global source + swizzled ds_read.
// NOTE: no sched_barrier after lgkmcnt(0) - reads are compiler-visible;
// pinning the scheduler there is the m141 regression pattern.
// ---------------------------------------------------------------------------
__global__ __launch_bounds__(512, 2) void gemm8p_kernel(
    const bf16_t* __restrict__ A, const bf16_t* __restrict__ B,
    const float* __restrict__ bsel, float* __restrict__ C)
{
    __shared__ __attribute__((aligned(16))) bf16_t As[2][2][HALF_E];
    __shared__ __attribute__((aligned(16))) bf16_t Bs[2][2][HALF_E];

    const int tid  = threadIdx.x;
    const int w    = tid >> 6;
    const int lane = tid & 63;
    const int wr   = w >> 2;            // 0..1 -> 128-row A strip (= A half)
    const int wc   = w & 3;             // 0..3 -> 64-col B strip (half = wc>>1)

    // XCD swizzle: n-panel chunk per XCD, m fastest (1024 % 8 == 0)
    const int bid = blockIdx.x;
    const int swz = (bid & 7) * 128 + (bid >> 3);
    const int m0 = (swz & 31) * BM;
    const int n0 = (swz >> 5) * BN;

    // staging source (inverse XOR slot swizzle; LDS dest linear)
    const int pr  = lane >> 3;                  // phys row within 8-row load
    const int csw = ((lane & 7) ^ pr) * 8;      // logical col for phys slot
    const bf16_t* aSrc[2][2];
    const bf16_t* bSrc[2][2];
#pragma unroll
    for (int h = 0; h < 2; ++h)
#pragma unroll
        for (int j = 0; j < 2; ++j) {
            const int row = h * 128 + (w * 2 + j) * 8 + pr;
            aSrc[h][j] = A + (long)(m0 + row) * IN_F + csw;
            bSrc[h][j] = B + (long)(n0 + row) * IN_F + csw;
        }

#define STAGE_A(buf, h, tl) do {                                               \
    __builtin_amdgcn_global_load_lds(GLOBAL_CAST(aSrc[h][0] + (long)(tl)*BK),  \
        LDS_CAST(&As[buf][h][(w * 2 + 0) * 512]), 16, 0, 0);                   \
    __builtin_amdgcn_global_load_lds(GLOBAL_CAST(aSrc[h][1] + (long)(tl)*BK),  \
        LDS_CAST(&As[buf][h][(w * 2 + 1) * 512]), 16, 0, 0);                   \
} while (0)
#define STAGE_B(buf, h, tl) do {                                               \
    __builtin_amdgcn_global_load_lds(GLOBAL_CAST(bSrc[h][0] + (long)(tl)*BK),  \
        LDS_CAST(&Bs[buf][h][(w * 2 + 0) * 512]), 16, 0, 0);                   \
    __builtin_amdgcn_global_load_lds(GLOBAL_CAST(bSrc[h][1] + (long)(tl)*BK),  \
        LDS_CAST(&Bs[buf][h][(w * 2 + 1) * 512]), 16, 0, 0);                   \
} while (0)

    f32x4 acc[8][4];
#pragma unroll
    for (int m = 0; m < 8; ++m)
#pragma unroll
        for (int n = 0; n < 4; ++n)
#pragma unroll
            for (int j = 0; j < 4; ++j) acc[m][n][j] = 0.f;

    const int fr    = lane & 15;
    const int kslot = lane >> 4;
    // swizzled slot byte-offsets for kk=0 / kk=32 (slot = kk/8 + kslot)
    const int sp0 = ((kslot     ^ (fr & 7)) << 3);
    const int sp1 = (((4+kslot) ^ (fr & 7)) << 3);

    bf16x8 af[4][2], bg[4][2];

#define RDA(buf, mq) do {                                                      \
    _Pragma("unroll") for (int mm = 0; mm < 4; ++mm) {                         \
        const int r = ((mq) * 4 + mm) * 16 + fr;                               \
        af[mm][0] = *(const bf16x8*)&As[buf][wr][r * 64 + sp0];                \
        af[mm][1] = *(const bf16x8*)&As[buf][wr][r * 64 + sp1];                \
    } } while (0)
#define RDB(buf, nh) do {                                                      \
    _Pragma("unroll") for (int nn = 0; nn < 2; ++nn) {                         \
        const int r = (wc & 1) * 64 + ((nh) * 2 + nn) * 16 + fr;               \
        bg[(nh)*2+nn][0] = *(const bf16x8*)&Bs[buf][wc >> 1][r * 64 + sp0];    \
        bg[(nh)*2+nn][1] = *(const bf16x8*)&Bs[buf][wc >> 1][r * 64 + sp1];    \
    } } while (0)
#define MFMAQ(mq, nh) do {                                                     \
    __builtin_amdgcn_s_setprio(1);                                             \
    _Pragma("unroll") for (int mm = 0; mm < 4; ++mm)                           \
    _Pragma("unroll") for (int nn = 0; nn < 2; ++nn) {                         \
        const int m = (mq) * 4 + mm, n = (nh) * 2 + nn;                        \
        acc[m][n] = __builtin_amdgcn_mfma_f32_16x16x32_bf16(                   \
            af[mm][0], bg[n][0], acc[m][n], 0, 0, 0);                          \
        acc[m][n] = __builtin_amdgcn_mfma_f32_16x16x32_bf16(                   \
            af[mm][1], bg[n][1], acc[m][n], 0, 0, 0);                          \
    }                                                                          \
    __builtin_amdgcn_s_setprio(0); } while (0)
#define BAR()   __builtin_amdgcn_s_barrier()
#define LGKM0() asm volatile("s_waitcnt lgkmcnt(0)" ::: "memory")
#define VMC4()  asm volatile("s_waitcnt vmcnt(4)" ::: "memory")
#define VMC0()  asm volatile("s_waitcnt vmcnt(0)" ::: "memory")

    // prologue: tile0 (all 4 halves) + B0(1), A0(1); drain to 4 outstanding
    STAGE_A(0, 0, 0); STAGE_A(0, 1, 0); STAGE_B(0, 0, 0); STAGE_B(0, 1, 0);
    STAGE_B(1, 0, 1); STAGE_A(1, 0, 1);
    VMC4(); BAR();

    for (int I = 0; I < NT / 2; ++I) {
        const int t = 2 * I, u = t + 1;
        const bool s2 = (I < NT / 2 - 1);

        // ph1 (t,mq0,nh0)
        RDA(0, 0); RDB(0, 0); STAGE_A(1, 1, u);
        BAR(); LGKM0(); MFMAQ(0, 0); BAR();
        // ph2 (t,mq0,nh1)
        RDB(0, 1); STAGE_B(1, 1, u);
        BAR(); LGKM0(); MFMAQ(0, 1); BAR();
        // ph3 (t,mq1,nh0)
        RDA(0, 1); if (s2) STAGE_B(0, 0, t + 2);
        BAR(); LGKM0(); MFMAQ(1, 0); BAR();
        // ph4 (t,mq1,nh1) — counted tile-boundary wait (full drain in tail:
        // vmcnt(4) there would leave A11(u)/B11(u) unguaranteed for ph5/ph6)
        if (s2) STAGE_A(0, 0, t + 2);
        BAR(); MFMAQ(1, 1); if (s2) VMC4(); else VMC0(); BAR();
        // ph5 (u,mq0,nh0)
        RDA(1, 0); RDB(1, 0); if (s2) STAGE_A(0, 1, t + 2);
        BAR(); LGKM0(); MFMAQ(0, 0); BAR();
        // ph6 (u,mq0,nh1)
        RDB(1, 1); if (s2) STAGE_B(0, 1, t + 2);
        BAR(); LGKM0(); MFMAQ(0, 1); BAR();
        // ph7 (u,mq1,nh0)
        RDA(1, 1); if (s2) STAGE_B(1, 0, u + 2);
        BAR(); LGKM0(); MFMAQ(1, 0); BAR();
        // ph8 (u,mq1,nh1) — counted tile-boundary wait
        if (s2) STAGE_A(1, 0, u + 2);
        BAR(); MFMAQ(1, 1); if (s2) VMC4(); else VMC0(); BAR();
    }
    VMC0();

#undef STAGE_A
#undef STAGE_B
#undef RDA
#undef RDB
#undef MFMAQ
#undef BAR
#undef LGKM0
#undef VMC4
#undef VMC0

    // epilogue: +bias, fp32 store (mapping verified rounds 3-6)
    float b4[4];
#pragma unroll
    for (int n = 0; n < 4; ++n) b4[n] = bsel[n0 + wc * 64 + n * 16 + fr];

    const int rbase = m0 + wr * 128 + kslot * 4;
#pragma unroll
    for (int m = 0; m < 8; ++m)
#pragma unroll
        for (int n = 0; n < 4; ++n) {
            const int col = n0 + wc * 64 + n * 16 + fr;
#pragma unroll
            for (int j = 0; j < 4; ++j)
                C[(long)(rbase + m * 16 + j) * KSEL + col] = acc[m][n][j] + b4[n];
        }
}

// ---------------------------------------------------------------------------
// Fallback (ws too small): fp32-staged m97-structure GEMM (known-correct).
// ---------------------------------------------------------------------------
__global__ __launch_bounds__(256) void gemm_f32staged_kernel(
    const float* __restrict__ A, const float* __restrict__ W,
    const int* __restrict__ idx, const float* __restrict__ bsel,
    float* __restrict__ C)
{
    constexpr int FBM = 128, FBN = 128, BK2 = 32;
    __shared__ __attribute__((aligned(16))) float Asf[FBM * BK2];
    __shared__ __attribute__((aligned(16))) float Bsf[FBN * BK2];

    const int tid  = threadIdx.x;
    const int wave = tid >> 6;
    const int lane = tid & 63;
    const int wrf  = wave >> 1;
    const int wcf  = wave & 1;

    const int m0 = blockIdx.x * FBM;
    const int n0 = blockIdx.y * FBN;

    const int srow = lane >> 3;
    const int scol = (lane & 7) * 4;

    const float* aptr[4];
    const float* bptr[4];
#pragma unroll
    for (int i = 0; i < 4; ++i) {
        aptr[i] = A + (long)(m0 + wave * 32 + i * 8 + srow) * IN_F + scol;
        const int br = idx[n0 + wave * 32 + i * 8 + srow];
        bptr[i] = W + (long)br * IN_F + scol;
    }

    f32x4 acc[4][4];
#pragma unroll
    for (int m = 0; m < 4; ++m)
#pragma unroll
        for (int n = 0; n < 4; ++n)
#pragma unroll
            for (int j = 0; j < 4; ++j) acc[m][n][j] = 0.f;

    const int fr = lane & 15;
    const int fk = (lane >> 4) * 8;

    for (int k0 = 0; k0 < IN_F; k0 += BK2) {
#pragma unroll
        for (int i = 0; i < 4; ++i) {
            __builtin_amdgcn_global_load_lds(GLOBAL_CAST(aptr[i] + k0),
                LDS_CAST(&Asf[(wave * 32 + i * 8) * BK2]), 16, 0, 0);
            __builtin_amdgcn_global_load_lds(GLOBAL_CAST(bptr[i] + k0),
                LDS_CAST(&Bsf[(wave * 32 + i * 8) * BK2]), 16, 0, 0);
        }
        __syncthreads();

        bf16x8 af[4], bg[4];
#pragma unroll
        for (int m = 0; m < 4; ++m) {
            const float* p = &Asf[(wrf * 64 + m * 16 + fr) * BK2 + fk];
            f32x4 x = *(const f32x4*)p, y = *(const f32x4*)(p + 4);
#pragma unroll
            for (int j = 0; j < 4; ++j) { af[m][j] = (bf16_t)x[j]; af[m][4+j] = (bf16_t)y[j]; }
        }
#pragma unroll
        for (int n = 0; n < 4; ++n) {
            const float* p = &Bsf[(wcf * 64 + n * 16 + fr) * BK2 + fk];
            f32x4 x = *(const f32x4*)p, y = *(const f32x4*)(p + 4);
#pragma unroll
            for (int j = 0; j < 4; ++j) { bg[n][j] = (bf16_t)x[j]; bg[n][4+j] = (bf16_t)y[j]; }
        }
#pragma unroll
        for (int m = 0; m < 4; ++m)
#pragma unroll
            for (int n = 0; n < 4; ++n)
                acc[m][n] = __builtin_amdgcn_mfma_f32_16x16x32_bf16(
                    af[m], bg[n], acc[m][n], 0, 0, 0);
        __syncthreads();
    }

    float b4[4];
#pragma unroll
    for (int n = 0; n < 4; ++n) b4[n] = bsel[n0 + wcf * 64 + n * 16 + fr];

    const int rbase = m0 + wrf * 64 + (lane >> 4) * 4;
#pragma unroll
    for (int m = 0; m < 4; ++m)
#pragma unroll
        for (int n = 0; n < 4; ++n) {
            const int col = n0 + wcf * 64 + n * 16 + fr;
#pragma unroll
            for (int j = 0; j < 4; ++j)
                C[(long)(rbase + m * 16 + j) * KSEL + col] = acc[m][n][j] + b4[n];
        }
}

// ---------------------------------------------------------------------------
extern "C" void kernel_launch(void* const* d_in, const int* in_sizes, int n_in,
                              void* d_out, int out_size, void* d_ws, size_t ws_size,
                              hipStream_t stream)
{
    const float* data   = (const float*)d_in[0];
    const float* weight = (const float*)d_in[1];
    const float* bias   = (const float*)d_in[2];
    const int*   mask   = (const int*)d_in[3];
    float*       out    = (float*)d_out;

    char* ws = (char*)d_ws;
    int*   idx  = (int*)ws;
    float* bsel = (float*)(ws + (KSEL * 4));
    bf16_t* Ab  = (bf16_t*)(ws + (KSEL * 8));
    bf16_t* Wb  = Ab + A_ELEMS;

    const size_t NEED = (size_t)KSEL * 8 + (size_t)A_ELEMS * 2 * 2;

    build_idx_kernel<<<1, 1024, 0, stream>>>(mask, bias, idx, bsel);

    if (ws_size >= NEED) {
        convert_kernel<<<2048, 256, 0, stream>>>(data, weight, idx, Ab, Wb);
        gemm8p_kernel<<<1024, 512, 0, stream>>>(Ab, Wb, bsel, out);
    } else {
        dim3 grid(N_TOK / 128, KSEL / 128);
        gemm_f32staged_kernel<<<grid, 256, 0, stream>>>(data, weight, idx, bsel, out);
    }
}

// Round 8
// 721.082 us; speedup vs baseline: 1.0181x; 1.0181x over previous
//
#include <hip/hip_runtime.h>
#include <hip/hip_bf16.h>

typedef __bf16 bf16_t;
typedef __attribute__((ext_vector_type(8))) __bf16 bf16x8;
typedef __attribute__((ext_vector_type(4))) float f32x4;

constexpr int IN_F  = 4096;
constexpr int OUT_F = 16384;
constexpr int N_TOK = 8192;
constexpr int KSEL  = 8192;
constexpr long A_ELEMS = (long)N_TOK * IN_F;

constexpr int BM = 256, BN = 256, BK = 64;
constexpr int NT = IN_F / BK;        // 64 K-tiles
constexpr int HALF_E = 128 * BK;     // 8192 elems per half-tile

#define GLOBAL_CAST(p) (const __attribute__((address_space(1))) void*)(p)
#define LDS_CAST(p)    (__attribute__((address_space(3))) void*)(p)

// ---------------------------------------------------------------------------
// Kernel 1: idx[] = positions of mask==1 (ascending) + gather bias (fp32).
// ---------------------------------------------------------------------------
__global__ __launch_bounds__(1024) void build_idx_kernel(
    const int* __restrict__ mask, const float* __restrict__ bias,
    int* __restrict__ idx, float* __restrict__ bsel)
{
    const int t    = threadIdx.x;
    const int lane = t & 63;
    const int wave = t >> 6;
    const int base_i = t * 16;

    int m[16];
    const int4* mp = (const int4*)(mask + base_i);
#pragma unroll
    for (int v = 0; v < 4; ++v) {
        int4 q = mp[v];
        m[v*4+0] = q.x; m[v*4+1] = q.y; m[v*4+2] = q.z; m[v*4+3] = q.w;
    }
    int cnt = 0;
#pragma unroll
    for (int j = 0; j < 16; ++j) cnt += (m[j] != 0) ? 1 : 0;

    int incl = cnt;
#pragma unroll
    for (int d = 1; d < 64; d <<= 1) {
        int o = __shfl_up(incl, (unsigned)d);
        if (lane >= d) incl += o;
    }

    __shared__ int wsum[16];
    __shared__ int wbase[16];
    if (lane == 63) wsum[wave] = incl;
    __syncthreads();
    if (t == 0) {
        int s = 0;
        for (int w = 0; w < 16; ++w) { wbase[w] = s; s += wsum[w]; }
    }
    __syncthreads();

    int p = wbase[wave] + (incl - cnt);
#pragma unroll
    for (int j = 0; j < 16; ++j) {
        if (m[j]) {
            int i = base_i + j;
            idx[p]  = i;
            bsel[p] = bias[i];
            ++p;
        }
    }
}

// ---------------------------------------------------------------------------
// Kernel 2: fp32 -> bf16 convert; A straight, W gathered by idx.
// ---------------------------------------------------------------------------
__global__ __launch_bounds__(256) void convert_kernel(
    const float* __restrict__ A, const float* __restrict__ W,
    const int* __restrict__ idx,
    bf16_t* __restrict__ Ab, bf16_t* __restrict__ Wb)
{
    const long nvecA = A_ELEMS / 8;
    const long total = nvecA * 2;
    const long stride = (long)gridDim.x * blockDim.x;
    for (long v = (long)blockIdx.x * blockDim.x + threadIdx.x; v < total; v += stride) {
        const float4* src;
        bf16_t* dst;
        if (v < nvecA) {
            src = (const float4*)(A + v * 8);
            dst = Ab + v * 8;
        } else {
            long u = v - nvecA;
            int j = (int)(u >> 9);
            int k = (int)(u & 511) * 8;
            src = (const float4*)(W + (long)idx[j] * IN_F + k);
            dst = Wb + u * 8;
        }
        float4 x = src[0], y = src[1];
        bf16x8 o;
        o[0]=(bf16_t)x.x; o[1]=(bf16_t)x.y; o[2]=(bf16_t)x.z; o[3]=(bf16_t)x.w;
        o[4]=(bf16_t)y.x; o[5]=(bf16_t)y.y; o[6]=(bf16_t)y.z; o[7]=(bf16_t)y.w;
        *(bf16x8*)dst = o;
    }
}

// ---------------------------------------------------------------------------
// Kernel 3: 8-phase 256x256 GEMM, BK=64, 8 waves (2Mx4N), 2-deep dbuf.
// Staging at EARLIEST legal slots: tile t+2 fully staged at ph3 (B, after
// B(t)'s last read ph2) + ph4 (A, after A(t)'s last read ph3); tile t+3 at
// ph7+ph8. Boundary waits vmcnt(8): ph4 drains tile t+1 (issued prev-iter
// ph7/8, 4-5 phases of slack over HBM latency), ph8 drains t+2 (issued
// ph3/4). Tail iteration uses vmcnt(0) at ph4 (only 8 in flight there).
// XOR slot swizzle via pre-swizzled global source + swizzled ds_read.
// ---------------------------------------------------------------------------
__global__ __launch_bounds__(512, 2) void gemm8p_kernel(
    const bf16_t* __restrict__ A, const bf16_t* __restrict__ B,
    const float* __restrict__ bsel, float* __restrict__ C)
{
    __shared__ __attribute__((aligned(16))) bf16_t As[2][2][HALF_E];
    __shared__ __attribute__((aligned(16))) bf16_t Bs[2][2][HALF_E];

    const int tid  = threadIdx.x;
    const int w    = tid >> 6;
    const int lane = tid & 63;
    const int wr   = w >> 2;            // 0..1 -> 128-row A strip (= A half)
    const int wc   = w & 3;             // 0..3 -> 64-col B strip (half = wc>>1)

    // XCD swizzle: n-panel chunk per XCD, m fastest (1024 % 8 == 0)
    const int bid = blockIdx.x;
    const int swz = (bid & 7) * 128 + (bid >> 3);
    const int m0 = (swz & 31) * BM;
    const int n0 = (swz >> 5) * BN;

    // staging source (inverse XOR slot swizzle; LDS dest linear)
    const int pr  = lane >> 3;                  // phys row within 8-row load
    const int csw = ((lane & 7) ^ pr) * 8;      // logical col for phys slot
    const bf16_t* aSrc[2][2];
    const bf16_t* bSrc[2][2];
#pragma unroll
    for (int h = 0; h < 2; ++h)
#pragma unroll
        for (int j = 0; j < 2; ++j) {
            const int row = h * 128 + (w * 2 + j) * 8 + pr;
            aSrc[h][j] = A + (long)(m0 + row) * IN_F + csw;
            bSrc[h][j] = B + (long)(n0 + row) * IN_F + csw;
        }

#define STAGE_A(buf, h, tl) do {                                               \
    __builtin_amdgcn_global_load_lds(GLOBAL_CAST(aSrc[h][0] + (long)(tl)*BK),  \
        LDS_CAST(&As[buf][h][(w * 2 + 0) * 512]), 16, 0, 0);                   \
    __builtin_amdgcn_global_load_lds(GLOBAL_CAST(aSrc[h][1] + (long)(tl)*BK),  \
        LDS_CAST(&As[buf][h][(w * 2 + 1) * 512]), 16, 0, 0);                   \
} while (0)
#define STAGE_B(buf, h, tl) do {                                               \
    __builtin_amdgcn_global_load_lds(GLOBAL_CAST(bSrc[h][0] + (long)(tl)*BK),  \
        LDS_CAST(&Bs[buf][h][(w * 2 + 0) * 512]), 16, 0, 0);                   \
    __builtin_amdgcn_global_load_lds(GLOBAL_CAST(bSrc[h][1] + (long)(tl)*BK),  \
        LDS_CAST(&Bs[buf][h][(w * 2 + 1) * 512]), 16, 0, 0);                   \
} while (0)

    f32x4 acc[8][4];
#pragma unroll
    for (int m = 0; m < 8; ++m)
#pragma unroll
        for (int n = 0; n < 4; ++n)
#pragma unroll
            for (int j = 0; j < 4; ++j) acc[m][n][j] = 0.f;

    const int fr    = lane & 15;
    const int kslot = lane >> 4;
    // swizzled slot byte-offsets for kk=0 / kk=32 (slot = kk/8 + kslot)
    const int sp0 = ((kslot     ^ (fr & 7)) << 3);
    const int sp1 = (((4+kslot) ^ (fr & 7)) << 3);

    bf16x8 af[4][2], bg[4][2];

#define RDA(buf, mq) do {                                                      \
    _Pragma("unroll") for (int mm = 0; mm < 4; ++mm) {                         \
        const int r = ((mq) * 4 + mm) * 16 + fr;                               \
        af[mm][0] = *(const bf16x8*)&As[buf][wr][r * 64 + sp0];                \
        af[mm][1] = *(const bf16x8*)&As[buf][wr][r * 64 + sp1];                \
    } } while (0)
#define RDB(buf, nh) do {                                                      \
    _Pragma("unroll") for (int nn = 0; nn < 2; ++nn) {                         \
        const int r = (wc & 1) * 64 + ((nh) * 2 + nn) * 16 + fr;               \
        bg[(nh)*2+nn][0] = *(const bf16x8*)&Bs[buf][wc >> 1][r * 64 + sp0];    \
        bg[(nh)*2+nn][1] = *(const bf16x8*)&Bs[buf][wc >> 1][r * 64 + sp1];    \
    } } while (0)
#define MFMAQ(mq, nh) do {                                                     \
    __builtin_amdgcn_s_setprio(1);                                             \
    _Pragma("unroll") for (int mm = 0; mm < 4; ++mm)                           \
    _Pragma("unroll") for (int nn = 0; nn < 2; ++nn) {                         \
        const int m = (mq) * 4 + mm, n = (nh) * 2 + nn;                        \
        acc[m][n] = __builtin_amdgcn_mfma_f32_16x16x32_bf16(                   \
            af[mm][0], bg[n][0], acc[m][n], 0, 0, 0);                          \
        acc[m][n] = __builtin_amdgcn_mfma_f32_16x16x32_bf16(                   \
            af[mm][1], bg[n][1], acc[m][n], 0, 0, 0);                          \
    }                                                                          \
    __builtin_amdgcn_s_setprio(0); } while (0)
#define BAR()    __builtin_amdgcn_s_barrier()
#define LGKM0()  asm volatile("s_waitcnt lgkmcnt(0)" ::: "memory")
#define LGKMH()  asm volatile("s_waitcnt lgkmcnt(8)" ::: "memory")
#define VMC8()   asm volatile("s_waitcnt vmcnt(8)" ::: "memory")
#define VMC0()   asm volatile("s_waitcnt vmcnt(0)" ::: "memory")

    // prologue: stage tiles 0 and 1 fully (16 loads); drain tile 0, keep 1
    STAGE_A(0, 0, 0); STAGE_A(0, 1, 0); STAGE_B(0, 0, 0); STAGE_B(0, 1, 0);
    STAGE_A(1, 0, 1); STAGE_A(1, 1, 1); STAGE_B(1, 0, 1); STAGE_B(1, 1, 1);
    VMC8(); BAR();

    for (int I = 0; I < NT / 2; ++I) {
        const int t = 2 * I, u = t + 1;          // t even -> buf0, u odd -> buf1
        const bool s2 = (I < NT / 2 - 1);

        // ph1 (t,mq0,nh0): 12 ds_read
        RDA(0, 0); RDB(0, 0);
        LGKMH(); BAR(); LGKM0(); MFMAQ(0, 0); BAR();
        // ph2 (t,mq0,nh1): 4 ds_read  [last read of B(t)]
        RDB(0, 1);
        BAR(); LGKM0(); MFMAQ(0, 1); BAR();
        // ph3 (t,mq1,nh0): 8 ds_read [last read of A(t)] + stage B(t+2)
        RDA(0, 1); if (s2) { STAGE_B(0, 0, t + 2); STAGE_B(0, 1, t + 2); }
        BAR(); LGKM0(); MFMAQ(1, 0); BAR();
        // ph4 (t,mq1,nh1): stage A(t+2); boundary wait -> tile t+1 landed
        if (s2) { STAGE_A(0, 0, t + 2); STAGE_A(0, 1, t + 2); }
        BAR(); MFMAQ(1, 1); if (s2) VMC8(); else VMC0(); BAR();
        // ph5 (u,mq0,nh0): 12 ds_read
        RDA(1, 0); RDB(1, 0);
        LGKMH(); BAR(); LGKM0(); MFMAQ(0, 0); BAR();
        // ph6 (u,mq0,nh1): 4 ds_read  [last read of B(u)]
        RDB(1, 1);
        BAR(); LGKM0(); MFMAQ(0, 1); BAR();
        // ph7 (u,mq1,nh0): 8 ds_read [last read of A(u)] + stage B(u+2)
        RDA(1, 1); if (s2) { STAGE_B(1, 0, u + 2); STAGE_B(1, 1, u + 2); }
        BAR(); LGKM0(); MFMAQ(1, 0); BAR();
        // ph8 (u,mq1,nh1): stage A(u+2); boundary wait -> tile t+2 landed
        if (s2) { STAGE_A(1, 0, u + 2); STAGE_A(1, 1, u + 2); }
        BAR(); MFMAQ(1, 1); if (s2) VMC8(); else VMC0(); BAR();
    }
    VMC0();

#undef STAGE_A
#undef STAGE_B
#undef RDA
#undef RDB
#undef MFMAQ
#undef BAR
#undef LGKM0
#undef LGKMH
#undef VMC8
#undef VMC0

    // epilogue: +bias, fp32 store (mapping verified rounds 3-7)
    float b4[4];
#pragma unroll
    for (int n = 0; n < 4; ++n) b4[n] = bsel[n0 + wc * 64 + n * 16 + fr];

    const int rbase = m0 + wr * 128 + kslot * 4;
#pragma unroll
    for (int m = 0; m < 8; ++m)
#pragma unroll
        for (int n = 0; n < 4; ++n) {
            const int col = n0 + wc * 64 + n * 16 + fr;
#pragma unroll
            for (int j = 0; j < 4; ++j)
                C[(long)(rbase + m * 16 + j) * KSEL + col] = acc[m][n][j] + b4[n];
        }
}

// ---------------------------------------------------------------------------
// Fallback (ws too small): fp32-staged m97-structure GEMM (known-correct).
// ---------------------------------------------------------------------------
__global__ __launch_bounds__(256) void gemm_f32staged_kernel(
    const float* __restrict__ A, const float* __restrict__ W,
    const int* __restrict__ idx, const float* __restrict__ bsel,
    float* __restrict__ C)
{
    constexpr int FBM = 128, FBN = 128, BK2 = 32;
    __shared__ __attribute__((aligned(16))) float Asf[FBM * BK2];
    __shared__ __attribute__((aligned(16))) float Bsf[FBN * BK2];

    const int tid  = threadIdx.x;
    const int wave = tid >> 6;
    const int lane = tid & 63;
    const int wrf  = wave >> 1;
    const int wcf  = wave & 1;

    const int m0 = blockIdx.x * FBM;
    const int n0 = blockIdx.y * FBN;

    const int srow = lane >> 3;
    const int scol = (lane & 7) * 4;

    const float* aptr[4];
    const float* bptr[4];
#pragma unroll
    for (int i = 0; i < 4; ++i) {
        aptr[i] = A + (long)(m0 + wave * 32 + i * 8 + srow) * IN_F + scol;
        const int br = idx[n0 + wave * 32 + i * 8 + srow];
        bptr[i] = W + (long)br * IN_F + scol;
    }

    f32x4 acc[4][4];
#pragma unroll
    for (int m = 0; m < 4; ++m)
#pragma unroll
        for (int n = 0; n < 4; ++n)
#pragma unroll
            for (int j = 0; j < 4; ++j) acc[m][n][j] = 0.f;

    const int fr = lane & 15;
    const int fk = (lane >> 4) * 8;

    for (int k0 = 0; k0 < IN_F; k0 += BK2) {
#pragma unroll
        for (int i = 0; i < 4; ++i) {
            __builtin_amdgcn_global_load_lds(GLOBAL_CAST(aptr[i] + k0),
                LDS_CAST(&Asf[(wave * 32 + i * 8) * BK2]), 16, 0, 0);
            __builtin_amdgcn_global_load_lds(GLOBAL_CAST(bptr[i] + k0),
                LDS_CAST(&Bsf[(wave * 32 + i * 8) * BK2]), 16, 0, 0);
        }
        __syncthreads();

        bf16x8 af[4], bg[4];
#pragma unroll
        for (int m = 0; m < 4; ++m) {
            const float* p = &Asf[(wrf * 64 + m * 16 + fr) * BK2 + fk];
            f32x4 x = *(const f32x4*)p, y = *(const f32x4*)(p + 4);
#pragma unroll
            for (int j = 0; j < 4; ++j) { af[m][j] = (bf16_t)x[j]; af[m][4+j] = (bf16_t)y[j]; }
        }
#pragma unroll
        for (int n = 0; n < 4; ++n) {
            const float* p = &Bsf[(wcf * 64 + n * 16 + fr) * BK2 + fk];
            f32x4 x = *(const f32x4*)p, y = *(const f32x4*)(p + 4);
#pragma unroll
            for (int j = 0; j < 4; ++j) { bg[n][j] = (bf16_t)x[j]; bg[n][4+j] = (bf16_t)y[j]; }
        }
#pragma unroll
        for (int m = 0; m < 4; ++m)
#pragma unroll
            for (int n = 0; n < 4; ++n)
                acc[m][n] = __builtin_amdgcn_mfma_f32_16x16x32_bf16(
                    af[m], bg[n], acc[m][n], 0, 0, 0);
        __syncthreads();
    }

    float b4[4];
#pragma unroll
    for (int n = 0; n < 4; ++n) b4[n] = bsel[n0 + wcf * 64 + n * 16 + fr];

    const int rbase = m0 + wrf * 64 + (lane >> 4) * 4;
#pragma unroll
    for (int m = 0; m < 4; ++m)
#pragma unroll
        for (int n = 0; n < 4; ++n) {
            const int col = n0 + wcf * 64 + n * 16 + fr;
#pragma unroll
            for (int j = 0; j < 4; ++j)
                C[(long)(rbase + m * 16 + j) * KSEL + col] = acc[m][n][j] + b4[n];
        }
}

// ---------------------------------------------------------------------------
extern "C" void kernel_launch(void* const* d_in, const int* in_sizes, int n_in,
                              void* d_out, int out_size, void* d_ws, size_t ws_size,
                              hipStream_t stream)
{
    const float* data   = (const float*)d_in[0];
    const float* weight = (const float*)d_in[1];
    const float* bias   = (const float*)d_in[2];
    const int*   mask   = (const int*)d_in[3];
    float*       out    = (float*)d_out;

    char* ws = (char*)d_ws;
    int*   idx  = (int*)ws;
    float* bsel = (float*)(ws + (KSEL * 4));
    bf16_t* Ab  = (bf16_t*)(ws + (KSEL * 8));
    bf16_t* Wb  = Ab + A_ELEMS;

    const size_t NEED = (size_t)KSEL * 8 + (size_t)A_ELEMS * 2 * 2;

    build_idx_kernel<<<1, 1024, 0, stream>>>(mask, bias, idx, bsel);

    if (ws_size >= NEED) {
        convert_kernel<<<2048, 256, 0, stream>>>(data, weight, idx, Ab, Wb);
        gemm8p_kernel<<<1024, 512, 0, stream>>>(Ab, Wb, bsel, out);
    } else {
        dim3 grid(N_TOK / 128, KSEL / 128);
        gemm_f32staged_kernel<<<grid, 256, 0, stream>>>(data, weight, idx, bsel, out);
    }
}